// Round 12
// baseline (184.225 us; speedup 1.0000x reference)
//
#include <hip/hip_runtime.h>
#include <math.h>

#define NIN 91392        // 17*21*16*16
#define DIN 8
#define DOUT 16
#define NCHUNK (NIN / 8) // 11424 chunks of 8 n
#define GRID_P 1024      // 4 blocks/CU persistent
#define TPB 512          // 8 waves; wave w owns batches {2w, 2w+1}

// async global->LDS, width 16 (m97 pattern): LDS dst = uniform base + lane*16
#define GLD_LDS16(gp, lp) __builtin_amdgcn_global_load_lds(                    \
    (const __attribute__((address_space(1))) float*)(gp),                      \
    (__attribute__((address_space(3))) float*)(lp), 16, 0, 0)

// Pass kernel: recompute u_hat[j,n,o] = sum_i x[b,n,i]*W[j,n,i,o] on the fly.
// R11 post-mortem: VGPR=32 -> compiler serializes all global loads (VALUBusy
// 10%, 1.2TB/s). Fix: W tile (8KB/chunk, was read 8x redundantly by the 8
// waves) is DMA'd once into LDS via global_load_lds (no VGPR round-trip),
// double-buffered so tile t+1 streams while tile t computes.
// Swizzle (rule #21, T2): LDS write is linear (DMA), so the SOURCE lane addr
// carries the XOR (slot^row&7) and the read applies the same XOR; otherwise
// the [row][i][og] ds_read_b128 pattern is a 16-way bank conflict.
// lane = (g:3)(j:1)(og:2); wave owns 2 batches; x loads stay direct (unique).
// PASS 0: s0 partial = sum_n u. PASS>0: c = sigmoid(sgn*d), 3-shuffle d.
template<int PASS>
__global__ __launch_bounds__(TPB) void caps_pass(
    const float* __restrict__ x, const float* __restrict__ W,
    const float* __restrict__ vin, float* __restrict__ part, int grid)
{
    const int t = threadIdx.x;
    const int lane = t & 63;
    const int wave = t >> 6;          // 0..7
    const int og = lane & 3;          // o-group: o = og*4..og*4+3
    const int j  = (lane >> 2) & 1;   // capsule
    const int g  = lane >> 3;         // n within chunk, 0..7
    const int bid = blockIdx.x;
    const int b0 = wave * 2;

    __shared__ __align__(16) float4 ldsW[1024];   // 2 bufs x 512 f4 = 16 KB

    // staging map: wave w, lane l writes LDS f4 pos p = w*64+l (linear).
    // row sr = p>>5 (= j*8+nn), stored slot s' = l&31, content slot = s'^(sr&7)
    const int sr  = wave * 2 + (lane >> 5);       // 0..15
    const int snn = sr & 7;
    const size_t sWbase = ((size_t)(sr >> 3) * NIN + snn) * 128
                        + (size_t)(((lane & 31) ^ snn) * 4);

    const float sgn = j ? -1.f : 1.f;

    float4 vin4[2];
    if (PASS > 0) {
        #pragma unroll
        for (int b = 0; b < 2; ++b) {
            float4 v = *(const float4*)(vin + (b0 + b) * 32 + j * 16 + og * 4);
            vin4[b] = make_float4(sgn * v.x, sgn * v.y, sgn * v.z, sgn * v.w);
        }
    }

    float4 acc0 = make_float4(0.f, 0.f, 0.f, 0.f);
    float4 acc1 = make_float4(0.f, 0.f, 0.f, 0.f);

    // prologue: DMA first tile into buf 0 (chunk c -> +c*1024 floats)
    if (bid < NCHUNK)
        GLD_LDS16(W + sWbase + (size_t)bid * 1024, (float*)(ldsW + wave * 64));
    asm volatile("s_waitcnt vmcnt(0)" ::: "memory");
    __syncthreads();

    int cur = 0;
    for (int c = bid; c < NCHUNK; c += grid) {
        // issue next tile's DMA into the other buffer (overlaps compute)
        const int cn = c + grid;
        if (cn < NCHUNK)
            GLD_LDS16(W + sWbase + (size_t)cn * 1024,
                      (float*)(ldsW + (cur ^ 1) * 512 + wave * 64));

        // ---- compute tile c from LDS ----
        const int n = c * 8 + g;
        const float* xp0 = x + ((size_t)(b0 + 0) * NIN + n) * DIN;
        const float* xp1 = x + ((size_t)(b0 + 1) * NIN + n) * DIN;
        float x0[DIN], x1[DIN];
        {
            const float4 a  = *(const float4*)(xp0);
            const float4 c4 = *(const float4*)(xp0 + 4);
            x0[0]=a.x;  x0[1]=a.y;  x0[2]=a.z;  x0[3]=a.w;
            x0[4]=c4.x; x0[5]=c4.y; x0[6]=c4.z; x0[7]=c4.w;
            const float4 a1 = *(const float4*)(xp1);
            const float4 c1 = *(const float4*)(xp1 + 4);
            x1[0]=a1.x; x1[1]=a1.y; x1[2]=a1.z; x1[3]=a1.w;
            x1[4]=c1.x; x1[5]=c1.y; x1[6]=c1.z; x1[7]=c1.w;
        }

        const float4* wb = ldsW + cur * 512 + ((j * 8 + g) << 5);
        float4 u0 = make_float4(0.f, 0.f, 0.f, 0.f);
        float4 u1 = make_float4(0.f, 0.f, 0.f, 0.f);
        #pragma unroll
        for (int i = 0; i < DIN; ++i) {
            const float4 w4 = wb[(((i << 2) | og)) ^ g];   // un-swizzle read
            u0.x += x0[i] * w4.x;  u0.y += x0[i] * w4.y;
            u0.z += x0[i] * w4.z;  u0.w += x0[i] * w4.w;
            u1.x += x1[i] * w4.x;  u1.y += x1[i] * w4.y;
            u1.z += x1[i] * w4.z;  u1.w += x1[i] * w4.w;
        }

        if (PASS == 0) {
            acc0.x += u0.x; acc0.y += u0.y; acc0.z += u0.z; acc0.w += u0.w;
            acc1.x += u1.x; acc1.y += u1.y; acc1.z += u1.z; acc1.w += u1.w;
        } else {
            // d = b_0 - b_1 over (j,o) = lane bits 0..2 butterfly
            float m0 = vin4[0].x*u0.x + vin4[0].y*u0.y + vin4[0].z*u0.z + vin4[0].w*u0.w;
            float m1 = vin4[1].x*u1.x + vin4[1].y*u1.y + vin4[1].z*u1.z + vin4[1].w*u1.w;
            m0 += __shfl_xor(m0, 1);  m1 += __shfl_xor(m1, 1);
            m0 += __shfl_xor(m0, 2);  m1 += __shfl_xor(m1, 2);
            m0 += __shfl_xor(m0, 4);  m1 += __shfl_xor(m1, 4);
            const float c0 = __builtin_amdgcn_rcpf(1.f + __expf(-sgn * m0));
            const float c1 = __builtin_amdgcn_rcpf(1.f + __expf(-sgn * m1));
            acc0.x += c0 * u0.x; acc0.y += c0 * u0.y;
            acc0.z += c0 * u0.z; acc0.w += c0 * u0.w;
            acc1.x += c1 * u1.x; acc1.y += c1 * u1.y;
            acc1.z += c1 * u1.z; acc1.w += c1 * u1.w;
        }

        // drain DMA + sync: buf[cur^1] now valid, buf[cur] free for next DMA
        asm volatile("s_waitcnt vmcnt(0)" ::: "memory");
        __syncthreads();
        cur ^= 1;
    }

    // g-reduction (lane bits 3..5), pure shuffles, no LDS
    #pragma unroll
    for (int s = 8; s <= 32; s <<= 1) {
        acc0.x += __shfl_xor(acc0.x, s); acc0.y += __shfl_xor(acc0.y, s);
        acc0.z += __shfl_xor(acc0.z, s); acc0.w += __shfl_xor(acc0.w, s);
        acc1.x += __shfl_xor(acc1.x, s); acc1.y += __shfl_xor(acc1.y, s);
        acc1.z += __shfl_xor(acc1.z, s); acc1.w += __shfl_xor(acc1.w, s);
    }
    if (g == 0) {
        // column-major partials: part[col][bid], col = b*32 + j*16 + o
        const size_t c0 = ((size_t)(b0 + 0) * 32 + j * 16 + og * 4) * grid + bid;
        const size_t c1 = ((size_t)(b0 + 1) * 32 + j * 16 + og * 4) * grid + bid;
        part[c0 + 0 * (size_t)grid] = acc0.x;  part[c0 + 1 * (size_t)grid] = acc0.y;
        part[c0 + 2 * (size_t)grid] = acc0.z;  part[c0 + 3 * (size_t)grid] = acc0.w;
        part[c1 + 0 * (size_t)grid] = acc1.x;  part[c1 + 1 * (size_t)grid] = acc1.y;
        part[c1 + 2 * (size_t)grid] = acc1.z;  part[c1 + 3 * (size_t)grid] = acc1.w;
    }
}

// Reduce partials -> s[b,j,o], squash -> v. 32 blocks = one per (b,j).
// PASS 0: scale 0.5 (uniform softmax), write v0
// PASS 1: write v0+v1 (logits linear in accumulated v)
// PASS 2: write final v
template<int PASS>
__global__ __launch_bounds__(256) void caps_reduce(
    const float* __restrict__ part, const float* __restrict__ vprev,
    float* __restrict__ vout, int gridA)
{
    const int blk = blockIdx.x;   // b*2 + j
    const int b = blk >> 1, j = blk & 1;
    const int t = threadIdx.x;
    const int o = t & 15;
    const int ch = t >> 4;
    const size_t base = ((size_t)b * 32 + j * 16 + o) * gridA;
    float s = 0.f;
    for (int g = ch; g < gridA; g += 16) s += part[base + g];
    __shared__ float red[256];
    red[t] = s;
    __syncthreads();
    if (t < 16) {
        float sv = 0.f;
        #pragma unroll
        for (int c = 0; c < 16; ++c) sv += red[c * 16 + t];
        if (PASS == 0) sv *= 0.5f;
        float sq = sv * sv;
        sq += __shfl_xor(sq, 1);
        sq += __shfl_xor(sq, 2);
        sq += __shfl_xor(sq, 4);
        sq += __shfl_xor(sq, 8);
        const float sn = sq;
        float v = sv * sn / ((1.f + sn) * sqrtf(sn + 1e-7f));
        if (PASS == 1) v += vprev[b * 32 + j * 16 + o];
        vout[b * 32 + j * 16 + o] = v;
    }
}

extern "C" void kernel_launch(void* const* d_in, const int* in_sizes, int n_in,
                              void* d_out, int out_size, void* d_ws, size_t ws_size,
                              hipStream_t stream) {
    const float* x = (const float*)d_in[0];
    const float* W = (const float*)d_in[1];
    float* out = (float*)d_out;

    // persistent grid; clamp to workspace (part = 512*GRID floats)
    size_t maxg = (ws_size - 4096) / (512 * sizeof(float));
    int GRID = (int)(maxg < GRID_P ? maxg : GRID_P);
    if (GRID < 1) GRID = 1;

    float* part = (float*)d_ws;                       // 512*GRID floats (2 MB)
    float* v0   = part + (size_t)512 * GRID;          // 512
    float* vsum = v0 + 512;                           // 512

    caps_pass<0><<<GRID, TPB, 0, stream>>>(x, W, nullptr, part, GRID);
    caps_reduce<0><<<32, 256, 0, stream>>>(part, nullptr, v0, GRID);
    caps_pass<1><<<GRID, TPB, 0, stream>>>(x, W, v0, part, GRID);
    caps_reduce<1><<<32, 256, 0, stream>>>(part, v0, vsum, GRID);
    caps_pass<2><<<GRID, TPB, 0, stream>>>(x, W, vsum, part, GRID);
    caps_reduce<2><<<32, 256, 0, stream>>>(part, nullptr, out, GRID);
}

// Round 13
// 137.610 us; speedup vs baseline: 1.3387x; 1.3387x over previous
//
#include <hip/hip_runtime.h>
#include <math.h>

#define NIN 91392        // 17*21*16*16
#define DIN 8
#define DOUT 16
#define NCHUNK (NIN / 8) // 11424 chunks of 8 n
#define GRID_P 1024      // 4 blocks/CU persistent
#define TPB 512          // 8 waves; wave w owns n-row w of each chunk

// async global->LDS, width 16: LDS dst wave-uniform, source per-lane (m173)
#define GLD_LDS16(gp, lp) __builtin_amdgcn_global_load_lds(                    \
    (const __attribute__((address_space(1))) float*)(gp),                      \
    (__attribute__((address_space(3))) float*)(lp), 16, 0, 0)

// R12 post-mortem: DS pipe was the wall -- each of 8 waves read the whole 8KB
// W tile (2-batch-per-wave split) = 8x LDS amplification + 8.77M bank-conflict
// cycles. NEW SPLIT: wave w owns n-row w (all 16 batches); lane = (b:4)(og:2).
//  - W LDS reads: wave reads only its own 1KB row; og-lanes share addresses
//    -> hardware broadcast, conflict-free, no swizzle.
//  - thread holds BOTH j capsules -> d[b,n] = 2 shuffles; sigmoids local.
//  - per-wave private LDS double-buffer -> NO __syncthreads in main loop;
//    counted vmcnt(3) keeps next tile's DMA + x prefetch in flight (T4).
// PASS 0: s0 partial = sum_n u. PASS>0: c_j = sigmoid(+-d), s_j partial.
template<int PASS>
__global__ __launch_bounds__(TPB) void caps_pass(
    const float* __restrict__ x, const float* __restrict__ W,
    const float* __restrict__ vin, float* __restrict__ part, int grid)
{
    const int t = threadIdx.x;
    const int lane = t & 63;
    const int wave = t >> 6;          // 0..7 = n-row within chunk
    const int b  = lane >> 2;         // batch 0..15
    const int og = lane & 3;          // o-group of 4
    const int bid = blockIdx.x;

    __shared__ __align__(16) float4 ldsW[1024];   // 8 waves x 2 bufs x 64 f4 = 16 KB
    __shared__ float lds2[8 * 576];               // epilogue reduce, stride-9 pad

    // DMA source: lane l stages W[(l>>5)*NIN + n][(l&31)*4 ..+3]  (j halves)
    const size_t wsrc_lane = (size_t)(lane >> 5) * ((size_t)NIN * 128)
                           + (size_t)(lane & 31) * 4;

    float4 vin0, vin1;                // vin[b][j][og*4..], j = 0 / 1
    if (PASS > 0) {
        vin0 = *(const float4*)(vin + b * 32 + 0  + og * 4);
        vin1 = *(const float4*)(vin + b * 32 + 16 + og * 4);
    }

    float4 accA = make_float4(0.f,0.f,0.f,0.f);   // j=0
    float4 accB = make_float4(0.f,0.f,0.f,0.f);   // j=1

    // prologue: stage chunk bid's row + x
    float4 xa, xb, xan, xbn;
    {
        const int n0 = bid * 8 + wave;
        GLD_LDS16(W + (size_t)n0 * 128 + wsrc_lane, (float*)(ldsW + wave * 128));
        const float* xp = x + ((size_t)b * NIN + n0) * DIN;
        xa = *(const float4*)(xp);
        xb = *(const float4*)(xp + 4);
    }

    int cur = 0;
    for (int c = bid; c < NCHUNK; c += grid) {
        const int cn = c + grid;
        if (cn < NCHUNK) {
            const int nn = cn * 8 + wave;
            GLD_LDS16(W + (size_t)nn * 128 + wsrc_lane,
                      (float*)(ldsW + wave * 128 + (cur ^ 1) * 64));
            const float* xp = x + ((size_t)b * NIN + nn) * DIN;
            xan = *(const float4*)(xp);
            xbn = *(const float4*)(xp + 4);
            // queue: [DMA_cur, xa, xb, DMA_next, xan, xbn] -> keep 3 newest
            asm volatile("s_waitcnt vmcnt(3)" ::: "memory");
        } else {
            asm volatile("s_waitcnt vmcnt(0)" ::: "memory");
        }

        // ---- compute row (all 16 b, both j, own 4 o) from own LDS buf ----
        const float4* wb = ldsW + wave * 128 + cur * 64;
        const float xr[8] = {xa.x, xa.y, xa.z, xa.w, xb.x, xb.y, xb.z, xb.w};
        float4 u0 = make_float4(0.f,0.f,0.f,0.f);
        float4 u1 = make_float4(0.f,0.f,0.f,0.f);
        #pragma unroll
        for (int i = 0; i < DIN; ++i) {
            const float4 w0 = wb[i * 4 + og];        // j=0, broadcast over b
            const float4 w1 = wb[32 + i * 4 + og];   // j=1
            u0.x += xr[i]*w0.x; u0.y += xr[i]*w0.y;
            u0.z += xr[i]*w0.z; u0.w += xr[i]*w0.w;
            u1.x += xr[i]*w1.x; u1.y += xr[i]*w1.y;
            u1.z += xr[i]*w1.z; u1.w += xr[i]*w1.w;
        }

        if (PASS == 0) {
            accA.x += u0.x; accA.y += u0.y; accA.z += u0.z; accA.w += u0.w;
            accB.x += u1.x; accB.y += u1.y; accB.z += u1.z; accB.w += u1.w;
        } else {
            // d = logit0 - logit1, reduced over the 4 og lanes (bits 0..1)
            float m = vin0.x*u0.x + vin0.y*u0.y + vin0.z*u0.z + vin0.w*u0.w
                    - (vin1.x*u1.x + vin1.y*u1.y + vin1.z*u1.z + vin1.w*u1.w);
            m += __shfl_xor(m, 1);
            m += __shfl_xor(m, 2);
            const float c0 = __builtin_amdgcn_rcpf(1.f + __expf(-m));
            const float c1 = __builtin_amdgcn_rcpf(1.f + __expf(m));
            accA.x += c0*u0.x; accA.y += c0*u0.y;
            accA.z += c0*u0.z; accA.w += c0*u0.w;
            accB.x += c1*u1.x; accB.y += c1*u1.y;
            accB.z += c1*u1.z; accB.w += c1*u1.w;
        }

        xa = xan; xb = xbn;
        cur ^= 1;
    }

    // ---- epilogue: cross-wave (n-row) reduce via padded LDS ----
    __syncthreads();
    {
        float* sl = lds2 + wave * 576 + lane * 9;
        sl[0]=accA.x; sl[1]=accA.y; sl[2]=accA.z; sl[3]=accA.w;
        sl[4]=accB.x; sl[5]=accB.y; sl[6]=accB.z; sl[7]=accB.w;
    }
    __syncthreads();
    if (t < 64) {
        float s[8];
        #pragma unroll
        for (int k = 0; k < 8; ++k) s[k] = 0.f;
        #pragma unroll
        for (int w = 0; w < 8; ++w) {
            const float* p = lds2 + w * 576 + t * 9;
            #pragma unroll
            for (int k = 0; k < 8; ++k) s[k] += p[k];
        }
        const int bb = t >> 2, oo = t & 3;
        #pragma unroll
        for (int k = 0; k < 8; ++k) {
            const int j = k >> 2, q = k & 3;
            // column-major partials: part[col][bid]
            part[(size_t)(bb * 32 + j * 16 + oo * 4 + q) * grid + bid] = s[k];
        }
    }
}

// Reduce partials -> s[b,j,o], squash -> v. 32 blocks = one per (b,j).
// PASS 0: scale 0.5 (uniform softmax), write v0
// PASS 1: write v0+v1 (logits linear in accumulated v)
// PASS 2: write final v
template<int PASS>
__global__ __launch_bounds__(256) void caps_reduce(
    const float* __restrict__ part, const float* __restrict__ vprev,
    float* __restrict__ vout, int gridA)
{
    const int blk = blockIdx.x;   // b*2 + j
    const int b = blk >> 1, j = blk & 1;
    const int t = threadIdx.x;
    const int o = t & 15;
    const int ch = t >> 4;
    const size_t base = ((size_t)b * 32 + j * 16 + o) * gridA;
    float s = 0.f;
    for (int g = ch; g < gridA; g += 16) s += part[base + g];
    __shared__ float red[256];
    red[t] = s;
    __syncthreads();
    if (t < 16) {
        float sv = 0.f;
        #pragma unroll
        for (int c = 0; c < 16; ++c) sv += red[c * 16 + t];
        if (PASS == 0) sv *= 0.5f;
        float sq = sv * sv;
        sq += __shfl_xor(sq, 1);
        sq += __shfl_xor(sq, 2);
        sq += __shfl_xor(sq, 4);
        sq += __shfl_xor(sq, 8);
        const float sn = sq;
        float v = sv * sn / ((1.f + sn) * sqrtf(sn + 1e-7f));
        if (PASS == 1) v += vprev[b * 32 + j * 16 + o];
        vout[b * 32 + j * 16 + o] = v;
    }
}

extern "C" void kernel_launch(void* const* d_in, const int* in_sizes, int n_in,
                              void* d_out, int out_size, void* d_ws, size_t ws_size,
                              hipStream_t stream) {
    const float* x = (const float*)d_in[0];
    const float* W = (const float*)d_in[1];
    float* out = (float*)d_out;

    // persistent grid; clamp to workspace (part = 512*GRID floats)
    size_t maxg = (ws_size - 4096) / (512 * sizeof(float));
    int GRID = (int)(maxg < GRID_P ? maxg : GRID_P);
    if (GRID < 1) GRID = 1;

    float* part = (float*)d_ws;                       // 512*GRID floats (2 MB)
    float* v0   = part + (size_t)512 * GRID;          // 512
    float* vsum = v0 + 512;                           // 512

    caps_pass<0><<<GRID, TPB, 0, stream>>>(x, W, nullptr, part, GRID);
    caps_reduce<0><<<32, 256, 0, stream>>>(part, nullptr, v0, GRID);
    caps_pass<1><<<GRID, TPB, 0, stream>>>(x, W, v0, part, GRID);
    caps_reduce<1><<<32, 256, 0, stream>>>(part, v0, vsum, GRID);
    caps_pass<2><<<GRID, TPB, 0, stream>>>(x, W, vsum, part, GRID);
    caps_reduce<2><<<32, 256, 0, stream>>>(part, nullptr, out, GRID);
}